// Round 1
// baseline (216.948 us; speedup 1.0000x reference)
//
#include <hip/hip_runtime.h>

// Problem constants (from reference setup_inputs: mask [64, 512, 896] f32)
#define B 64
#define H 512
#define W 896
#define W4 (W / 4)                         // 224 float4 per row
#define PIX_PER_BATCH (H * W)              // 458752
#define VEC_PER_BATCH (PIX_PER_BATCH / 4)  // 114688
#define TPB 256
#define VEC_PER_THREAD 8
#define VEC_PER_BLOCK (TPB * VEC_PER_THREAD)            // 2048
#define BLOCKS_PER_BATCH (VEC_PER_BATCH / VEC_PER_BLOCK) // 56 (exact)
#define PROB_THRESHOLD 0.5f

struct BoxWs {
    int cnt[B];
    int rmn[B];
    int rmx[B];
    int cmn[B];
    int cmx[B];
};

// ---------------------------------------------------------------------------
// Kernel 0: init workspace sentinels (ws is poisoned 0xAA before every call)
// ---------------------------------------------------------------------------
__global__ void rag_init_kernel(BoxWs* __restrict__ ws) {
    int i = threadIdx.x;
    if (i < B) {
        ws->cnt[i] = 0;
        ws->rmn[i] = H;    // sentinel: min over empty set
        ws->rmx[i] = -1;
        ws->cmn[i] = W;
        ws->cmx[i] = -1;
    }
}

// ---------------------------------------------------------------------------
// Kernel 1: per-batch count + bbox reduction.
// grid = (BLOCKS_PER_BATCH, B), block = TPB. float4 coalesced reads.
// ---------------------------------------------------------------------------
__global__ __launch_bounds__(TPB) void rag_reduce_kernel(
        const float* __restrict__ mask, BoxWs* __restrict__ ws) {
    const int b = blockIdx.y;
    const float4* m = reinterpret_cast<const float4*>(mask + (size_t)b * PIX_PER_BATCH);
    const int base = blockIdx.x * VEC_PER_BLOCK + threadIdx.x;

    int cnt = 0;
    int rmn = H, rmx = -1, cmn = W, cmx = -1;

#pragma unroll
    for (int it = 0; it < VEC_PER_THREAD; ++it) {
        const int i4 = base + it * TPB;
        const float4 v = m[i4];
        const int row = i4 / W4;
        const int col = (i4 - row * W4) * 4;
        const bool f0 = v.x > PROB_THRESHOLD;
        const bool f1 = v.y > PROB_THRESHOLD;
        const bool f2 = v.z > PROB_THRESHOLD;
        const bool f3 = v.w > PROB_THRESHOLD;
        cnt += (int)f0 + (int)f1 + (int)f2 + (int)f3;
        if (f0 | f1 | f2 | f3) {
            rmn = min(rmn, row);
            rmx = max(rmx, row);
            const int clo = f0 ? col : (f1 ? col + 1 : (f2 ? col + 2 : col + 3));
            const int chi = f3 ? col + 3 : (f2 ? col + 2 : (f1 ? col + 1 : col));
            cmn = min(cmn, clo);
            cmx = max(cmx, chi);
        }
    }

    // Wave-64 butterfly-down reduce.
#pragma unroll
    for (int off = 32; off > 0; off >>= 1) {
        cnt += __shfl_down(cnt, off);
        rmn = min(rmn, __shfl_down(rmn, off));
        rmx = max(rmx, __shfl_down(rmx, off));
        cmn = min(cmn, __shfl_down(cmn, off));
        cmx = max(cmx, __shfl_down(cmx, off));
    }

    __shared__ int s[5][TPB / 64];
    const int wave = threadIdx.x >> 6;
    if ((threadIdx.x & 63) == 0) {
        s[0][wave] = cnt;
        s[1][wave] = rmn;
        s[2][wave] = rmx;
        s[3][wave] = cmn;
        s[4][wave] = cmx;
    }
    __syncthreads();
    if (threadIdx.x == 0) {
#pragma unroll
        for (int wv = 1; wv < TPB / 64; ++wv) {
            cnt += s[0][wv];
            rmn = min(rmn, s[1][wv]);
            rmx = max(rmx, s[2][wv]);
            cmn = min(cmn, s[3][wv]);
            cmx = max(cmx, s[4][wv]);
        }
        atomicAdd(&ws->cnt[b], cnt);
        atomicMin(&ws->rmn[b], rmn);
        atomicMax(&ws->rmx[b], rmx);
        atomicMin(&ws->cmn[b], cmn);
        atomicMax(&ws->cmx[b], cmx);
    }
}

// ---------------------------------------------------------------------------
// Kernel 2: fill attention map. grid = (BLOCKS_PER_BATCH, B).
// ---------------------------------------------------------------------------
__global__ __launch_bounds__(TPB) void rag_fill_kernel(
        const BoxWs* __restrict__ ws,
        const int* __restrict__ nthr_p,
        const int* __restrict__ dthr_p,
        float* __restrict__ out) {
    const int b = blockIdx.y;
    const int nthr = *nthr_p;
    const int dthr = *dthr_p;

    const bool enough = ws->cnt[b] >= nthr;
    const int rmn = max(ws->rmn[b] - dthr, 0);
    const int rmx = min(ws->rmx[b] + dthr, H - 1);
    const int cmn = max(ws->cmn[b] - dthr, 0);
    const int cmx = min(ws->cmx[b] + dthr, W - 1);

    float4* o = reinterpret_cast<float4*>(out + (size_t)b * PIX_PER_BATCH);
    const int base = blockIdx.x * VEC_PER_BLOCK + threadIdx.x;

#pragma unroll
    for (int it = 0; it < VEC_PER_THREAD; ++it) {
        const int i4 = base + it * TPB;
        const int row = i4 / W4;
        const int col = (i4 - row * W4) * 4;
        const bool rin = (row >= rmn) & (row <= rmx);
        float4 v;
        v.x = (!enough || (rin & (col + 0 >= cmn) & (col + 0 <= cmx))) ? 1.0f : 0.0f;
        v.y = (!enough || (rin & (col + 1 >= cmn) & (col + 1 <= cmx))) ? 1.0f : 0.0f;
        v.z = (!enough || (rin & (col + 2 >= cmn) & (col + 2 <= cmx))) ? 1.0f : 0.0f;
        v.w = (!enough || (rin & (col + 3 >= cmn) & (col + 3 <= cmx))) ? 1.0f : 0.0f;
        o[i4] = v;
    }
}

// ---------------------------------------------------------------------------
extern "C" void kernel_launch(void* const* d_in, const int* in_sizes, int n_in,
                              void* d_out, int out_size, void* d_ws, size_t ws_size,
                              hipStream_t stream) {
    const float* mask  = (const float*)d_in[0];
    const int*   nthr  = (const int*)d_in[1];
    const int*   dthr  = (const int*)d_in[2];
    float*       out   = (float*)d_out;
    BoxWs*       ws    = (BoxWs*)d_ws;

    rag_init_kernel<<<1, 256, 0, stream>>>(ws);

    dim3 grid(BLOCKS_PER_BATCH, B);
    rag_reduce_kernel<<<grid, TPB, 0, stream>>>(mask, ws);
    rag_fill_kernel<<<grid, TPB, 0, stream>>>(ws, nthr, dthr, out);
}

// Round 3
// 211.384 us; speedup vs baseline: 1.0263x; 1.0263x over previous
//
#include <hip/hip_runtime.h>

// Problem constants (reference setup_inputs: mask [64, 512, 896] f32)
#define B 64
#define H 512
#define W 896
#define W4 (W / 4)                  // 224 float4 per row
#define PIX (H * W)                 // 458752 per batch
#define VEC (PIX / 4)               // 114688 float4 per batch
#define TPB 256
#define SLICES 32                   // blocks per batch
#define VEC_SLICE (VEC / SLICES)    // 3584 float4 per block
#define ITERS (VEC_SLICE / TPB)     // 14 float4 per thread
#define NBLK (B * SLICES)           // 2048 blocks
#define PT 0.5f

// ws layout: int[5][NBLK] -> cnt, rmn, rmx, cmn, cmx partials, one slot per
// reduce-block (written exactly once -> no init kernel, no atomics needed).

// ---------------------------------------------------------------------------
// Kernel 1: per-slice count + bbox partials.
// ---------------------------------------------------------------------------
__global__ __launch_bounds__(TPB) void rag_reduce_kernel(
        const float* __restrict__ mask, int* __restrict__ ws) {
    const int bid = blockIdx.x;          // 0..NBLK-1
    const int b   = bid >> 5;            // batch (SLICES == 32)
    const int tid = threadIdx.x;
    const int sbase = (bid & (SLICES - 1)) * VEC_SLICE + tid;

    const float4* m = reinterpret_cast<const float4*>(mask) + (size_t)b * VEC;

    int cnt = 0, rmn = H, rmx = -1, cmn = W, cmx = -1;

#pragma unroll
    for (int it = 0; it < ITERS; ++it) {
        const int i4 = sbase + it * TPB;
        const float4 v = m[i4];
        const bool f0 = v.x > PT;
        const bool f1 = v.y > PT;
        const bool f2 = v.z > PT;
        const bool f3 = v.w > PT;
        cnt += (int)f0 + (int)f1 + (int)f2 + (int)f3;
        if (f0 | f1 | f2 | f3) {
            const int row = i4 / W4;
            const int col = (i4 - row * W4) * 4;
            rmn = min(rmn, row);
            rmx = max(rmx, row);
            const int clo = f0 ? col : (f1 ? col + 1 : (f2 ? col + 2 : col + 3));
            const int chi = f3 ? col + 3 : (f2 ? col + 2 : (f1 ? col + 1 : col));
            cmn = min(cmn, clo);
            cmx = max(cmx, chi);
        }
    }

    // Wave-64 reduce.
#pragma unroll
    for (int off = 32; off > 0; off >>= 1) {
        cnt += __shfl_down(cnt, off);
        rmn = min(rmn, __shfl_down(rmn, off));
        rmx = max(rmx, __shfl_down(rmx, off));
        cmn = min(cmn, __shfl_down(cmn, off));
        cmx = max(cmx, __shfl_down(cmx, off));
    }

    __shared__ int s[5][TPB / 64];
    const int wave = tid >> 6;
    if ((tid & 63) == 0) {
        s[0][wave] = cnt; s[1][wave] = rmn; s[2][wave] = rmx;
        s[3][wave] = cmn; s[4][wave] = cmx;
    }
    __syncthreads();
    if (tid == 0) {
#pragma unroll
        for (int wv = 1; wv < TPB / 64; ++wv) {
            cnt += s[0][wv];
            rmn = min(rmn, s[1][wv]);
            rmx = max(rmx, s[2][wv]);
            cmn = min(cmn, s[3][wv]);
            cmx = max(cmx, s[4][wv]);
        }
        ws[0 * NBLK + bid] = cnt;
        ws[1 * NBLK + bid] = rmn;
        ws[2 * NBLK + bid] = rmx;
        ws[3 * NBLK + bid] = cmn;
        ws[4 * NBLK + bid] = cmx;
    }
}

// ---------------------------------------------------------------------------
// Kernel 2: finalize box from partials (first wave) + stream output.
// ---------------------------------------------------------------------------
__global__ __launch_bounds__(TPB) void rag_fill_kernel(
        const int* __restrict__ ws,
        const int* __restrict__ nthr_p,
        const int* __restrict__ dthr_p,
        float* __restrict__ out) {
    const int bid = blockIdx.x;
    const int b   = bid >> 5;
    const int tid = threadIdx.x;

    __shared__ int sbox[4];
    if (tid < 64) {
        const int q = (b << 5) + (tid & 31);   // 32 partial slots for this batch
        int c  = ws[0 * NBLK + q];
        int r0 = ws[1 * NBLK + q];
        int r1 = ws[2 * NBLK + q];
        int c0 = ws[3 * NBLK + q];
        int c1 = ws[4 * NBLK + q];
#pragma unroll
        for (int off = 16; off > 0; off >>= 1) {
            c  += __shfl_xor(c, off, 32);
            r0 = min(r0, __shfl_xor(r0, off, 32));
            r1 = max(r1, __shfl_xor(r1, off, 32));
            c0 = min(c0, __shfl_xor(c0, off, 32));
            c1 = max(c1, __shfl_xor(c1, off, 32));
        }
        if (tid == 0) {
            const int nthr = *nthr_p;
            const int dthr = *dthr_p;
            int brmn, brmx, bcmn, bcmx;
            if (c >= nthr) {
                brmn = max(r0 - dthr, 0);
                brmx = min(r1 + dthr, H - 1);
                bcmn = max(c0 - dthr, 0);
                bcmx = min(c1 + dthr, W - 1);
            } else {  // too few points -> attend everywhere
                brmn = 0; brmx = H - 1; bcmn = 0; bcmx = W - 1;
            }
            sbox[0] = brmn; sbox[1] = brmx; sbox[2] = bcmn; sbox[3] = bcmx;
        }
    }
    __syncthreads();
    const int brmn = sbox[0], brmx = sbox[1], bcmn = sbox[2], bcmx = sbox[3];

    float4* ob = reinterpret_cast<float4*>(out) + (size_t)b * VEC;
    const int sbase = (bid & (SLICES - 1)) * VEC_SLICE + tid;

#pragma unroll
    for (int it = 0; it < ITERS; ++it) {
        const int i4 = sbase + it * TPB;
        const int row = i4 / W4;
        const int col = (i4 - row * W4) * 4;
        const bool rin = (row >= brmn) & (row <= brmx);
        float4 v;
        v.x = (rin & (col + 0 >= bcmn) & (col + 0 <= bcmx)) ? 1.0f : 0.0f;
        v.y = (rin & (col + 1 >= bcmn) & (col + 1 <= bcmx)) ? 1.0f : 0.0f;
        v.z = (rin & (col + 2 >= bcmn) & (col + 2 <= bcmx)) ? 1.0f : 0.0f;
        v.w = (rin & (col + 3 >= bcmn) & (col + 3 <= bcmx)) ? 1.0f : 0.0f;
        ob[i4] = v;
    }
}

// ---------------------------------------------------------------------------
extern "C" void kernel_launch(void* const* d_in, const int* in_sizes, int n_in,
                              void* d_out, int out_size, void* d_ws, size_t ws_size,
                              hipStream_t stream) {
    const float* mask = (const float*)d_in[0];
    const int*   nthr = (const int*)d_in[1];
    const int*   dthr = (const int*)d_in[2];
    float*       out  = (float*)d_out;
    int*         ws   = (int*)d_ws;

    rag_reduce_kernel<<<NBLK, TPB, 0, stream>>>(mask, ws);
    rag_fill_kernel<<<NBLK, TPB, 0, stream>>>(ws, nthr, dthr, out);
}